// Round 5
// baseline (208.083 us; speedup 1.0000x reference)
//
#include <hip/hip_runtime.h>
#include <cmath>

typedef __attribute__((ext_vector_type(8))) short short8;
typedef __attribute__((ext_vector_type(4))) float f32x4;

static __device__ __forceinline__ unsigned short f2bf(float x) {
  unsigned int u = __float_as_uint(x);
  unsigned int r = (u + 0x7FFFu + ((u >> 16) & 1u)) >> 16;
  return (unsigned short)r;
}
static __device__ __forceinline__ float bf2f(unsigned short u) {
  return __uint_as_float(((unsigned int)u) << 16);
}
static __device__ __forceinline__ void glds16(const unsigned short* g, unsigned short* l) {
  __builtin_amdgcn_global_load_lds((const __attribute__((address_space(1))) unsigned int*)(g),
                                   (__attribute__((address_space(3))) unsigned int*)(l), 16, 0, 0);
}

#define VWAIT(n) asm volatile("s_waitcnt vmcnt(" #n ")" ::: "memory")

// ---------- fused: cond = w@aw.T + ab (+ssum), and weight prep ---------------
__global__ __launch_bounds__(256) void k_pre1(const float* __restrict__ w,
    const float* __restrict__ aw, const float* __restrict__ ab,
    const float* __restrict__ cw, float* __restrict__ cond, float* __restrict__ ssum,
    float* __restrict__ W2, float* __restrict__ rinv, unsigned short* __restrict__ wpack) {
  __shared__ float red[4];
  int bid = blockIdx.x, t = threadIdx.x;
  if (bid < 128) {
    int outp = bid * 64 + (t >> 2);
    int sub = t & 3;
    int b = outp >> 9, i = outp & 511;
    const float4* wr = (const float4*)(w + b * 512);
    const float4* ar = (const float4*)(aw + i * 512);
    float acc = 0.f;
    #pragma unroll
    for (int jj = 0; jj < 32; ++jj) {
      int j = sub + jj * 4;
      float4 a = ar[j], v = wr[j];
      acc += a.x * v.x + a.y * v.y + a.z * v.z + a.w * v.w;
    }
    acc += __shfl_xor(acc, 1);
    acc += __shfl_xor(acc, 2);
    float s = 0.f;
    if (sub == 0) {
      float c = acc + ab[i];
      cond[outp] = c;
      s = c * c;
    }
    #pragma unroll
    for (int off = 4; off <= 32; off <<= 1) s += __shfl_xor(s, off);
    if ((t & 63) == 0) atomicAdd(ssum, s);
  } else {
    int o = bid - 128;
    const float* row = cw + o * 1536;
    float local = 0.f;
    for (int r = 0; r < 2; ++r) {
      int i = t + 256 * r;
      float a = row[3 * i], b = row[3 * i + 1], c = row[3 * i + 2];
      float w2 = a * a + b * b + c * c;
      W2[o * 512 + i] = w2;
      local += w2;
      int chunk = i >> 5;
      int laneo = (((i >> 3) & 3) << 4) + (o & 15);
      int e = i & 7;
      int base = (chunk * 32 + (o >> 4)) * 512 + laneo * 8 + e;  // k=0
      wpack[base] = f2bf(a);
      wpack[base + 16 * 32 * 512] = f2bf(b);        // k=1
      wpack[base + 2 * 16 * 32 * 512] = f2bf(c);    // k=2
    }
    #pragma unroll
    for (int off = 32; off >= 1; off >>= 1) local += __shfl_down(local, off);
    if ((t & 63) == 0) red[t >> 6] = local;
    __syncthreads();
    if (t == 0) {
      float m = red[0] + red[1] + red[2] + red[3];
      rinv[o] = rsqrtf(m * (1.f / 1536.f));
    }
  }
}

// ---------- fused: demod coef, and xsT transpose/pack ------------------------
__global__ __launch_bounds__(256) void k_pre2(const float* __restrict__ x,
    const float* __restrict__ W2, const float* __restrict__ cond,
    const float* __restrict__ rinv, const float* __restrict__ ssum,
    const float* __restrict__ nrm, float* __restrict__ coef,
    unsigned short* __restrict__ xsT) {
  __shared__ float shb[64 * 65];
  int bid = blockIdx.x, t = threadIdx.x;
  if (bid < 256) {
    int og = bid & 15, b = bid >> 4;
    int o = og * 32 + (t >> 3);
    int il = t & 7;
    float c0 = cond[b * 512 + t];
    float c1 = cond[b * 512 + t + 256];
    shb[t] = c0 * c0;
    shb[t + 256] = c1 * c1;
    __syncthreads();
    float acc = 0.f;
    #pragma unroll
    for (int jj = 0; jj < 16; ++jj) {
      int i = jj * 32 + il * 4;
      float4 wv = *(const float4*)(W2 + o * 512 + i);
      acc += wv.x * shb[i] + wv.y * shb[i + 1] + wv.z * shb[i + 2] + wv.w * shb[i + 3];
    }
    acc += __shfl_xor(acc, 1);
    acc += __shfl_xor(acc, 2);
    acc += __shfl_xor(acc, 4);
    if (il == 0) {
      float inv_ms = 8192.f / ssum[0];
      float ro = rinv[o];
      coef[b * 512 + o] = ro * rsqrtf(ro * ro * acc * inv_ms + 1e-8f);
    }
  } else {
    int xb = bid - 256;
    int lb = xb & 31, ib = (xb >> 5) & 7, b = xb >> 8;
    float (*tile)[65] = (float(*)[65])shb;
    int l0 = lb * 64, i0 = ib * 64;
    float sc = rsqrtf(ssum[0] * (1.f / 8192.f)) * rsqrtf(nrm[0]);
    int tr = t >> 4, tc = (t & 15) * 4;
    #pragma unroll
    for (int rr = 0; rr < 4; ++rr) {
      int il = rr * 16 + tr;
      float se = cond[b * 512 + i0 + il] * sc;
      float4 v = *(const float4*)(x + ((size_t)b * 512 + i0 + il) * 2048 + l0 + tc);
      tile[il][tc + 0] = v.x * se;
      tile[il][tc + 1] = v.y * se;
      tile[il][tc + 2] = v.z * se;
      tile[il][tc + 3] = v.w * se;
    }
    __syncthreads();
    int lr = t >> 3, ic = (t & 7) * 8;
    #pragma unroll
    for (int rr = 0; rr < 2; ++rr) {
      int ll = rr * 32 + lr;
      uint4 u;
      unsigned int pk[4];
      #pragma unroll
      for (int j = 0; j < 4; ++j) {
        unsigned short lo = f2bf(tile[ic + 2 * j][ll]);
        unsigned short hi = f2bf(tile[ic + 2 * j + 1][ll]);
        pk[j] = (unsigned int)lo | ((unsigned int)hi << 16);
      }
      u.x = pk[0]; u.y = pk[1]; u.z = pk[2]; u.w = pk[3];
      *(uint4*)(xsT + ((size_t)b * 2050 + 1 + l0 + ll) * 512 + i0 + ic) = u;
    }
    if (lb == 0 && t < 8) {
      uint4 z; z.x = 0; z.y = 0; z.z = 0; z.w = 0;
      *(uint4*)(xsT + ((size_t)b * 2050) * 512 + i0 + t * 8) = z;
    }
    if (lb == 31 && t < 8) {
      uint4 z; z.x = 0; z.y = 0; z.z = 0; z.w = 0;
      *(uint4*)(xsT + ((size_t)b * 2050 + 2049) * 512 + i0 + t * 8) = z;
    }
  }
}

// ----------------- main: y[b,o,l] = conv(xs, W)*coef + bias ------------------
// 128o x 128l tile, 4 waves (2x2). Period = 2 K-chunks (K=64) per barrier:
//   [A(2p) | S_a(p+1) | MFMA(2p) | A(2p+1) | S_b(p+1) | MFMA(2p+1) | vm0+bar]
// A (weights) single-buffered in regs (48 VGPR) — each compiler A-wait is a
// counted vmcnt leaving the S-prefetch in flight; the period-end vmcnt(0)
// only drains loads issued >=1 MFMA-step earlier. B double-period-buffered
// in LDS via global_load_lds with pre-swizzled global source.
// (256,2): R3 showed forcing 3 blocks/CU spills acc/A to scratch (4x slower).
#define STAGE_B(par, sub, c) { \
  _Pragma("unroll") for (int j_ = 0; j_ < 3; ++j_) { \
    int sb_ = wave * 130 + ((j_ < 2) ? j_ * 64 : 128); \
    int s_ = sb_ + ((j_ < 2) ? lane : (lane & 1)); \
    if (j_ < 2 || lane < 2) { \
      int col_ = ((s_ >> 3) << 1) | (((s_ >> 2) ^ (s_ >> 4)) & 1); \
      int q_ = ((s_ ^ (s_ >> 2) ^ (s_ >> 4)) & 1) | ((((s_ >> 1) ^ (s_ >> 3)) & 1) << 1); \
      const unsigned short* src_ = xsT + ((size_t)b * 2050 + l0 + col_) * 512 + (c) * 32 + q_ * 8; \
      glds16(src_, &Bl[par][sub][sb_ * 8]); \
    } \
  } }

#define LOAD_A(Ar, c) { \
  _Pragma("unroll") for (int k_ = 0; k_ < 3; ++k_) \
  _Pragma("unroll") for (int rg_ = 0; rg_ < 4; ++rg_) \
    Ar[k_ * 4 + rg_] = *(const short8*)(wpack + ((size_t)((k_ * 16 + (c)) * 32 + ob * 8 + wr * 4 + rg_)) * 512 + lane * 8); }

#define MFMA_STEP(Ar, par, sub) { \
  _Pragma("unroll") for (int k_ = 0; k_ < 3; ++k_) { \
    short8 bfr_[4]; \
    _Pragma("unroll") for (int cg_ = 0; cg_ < 4; ++cg_) { \
      int col_ = wc * 64 + cg_ * 16 + (lane & 15) + k_; \
      int byte_ = (col_ * 64 + ((lane >> 4) << 4)) ^ ((col_ & 7) << 4); \
      bfr_[cg_] = *(const short8*)((const char*)Bl[par][sub] + byte_); \
    } \
    _Pragma("unroll") for (int rg_ = 0; rg_ < 4; ++rg_) \
      _Pragma("unroll") for (int cg_ = 0; cg_ < 4; ++cg_) \
        acc[rg_][cg_] = __builtin_amdgcn_mfma_f32_16x16x32_bf16(Ar[k_ * 4 + rg_], bfr_[cg_], acc[rg_][cg_], 0, 0, 0); \
  } }

__global__ __launch_bounds__(256, 2) void k_main(const unsigned short* __restrict__ xsT,
    const unsigned short* __restrict__ wpack, const float* __restrict__ coef,
    const float* __restrict__ convb, unsigned short* __restrict__ y) {
  int lb = blockIdx.x, ob = blockIdx.y, b = blockIdx.z;
  int t = threadIdx.x, lane = t & 63, wave = t >> 6;
  int wr = wave >> 1, wc = wave & 1;
  int l0 = lb * 128, o0 = ob * 128;
  __shared__ __align__(16) unsigned short Bl[2][2][4160];  // 33,280 B
  f32x4 acc[4][4];
  f32x4 z4 = {0.f, 0.f, 0.f, 0.f};
  #pragma unroll
  for (int i = 0; i < 4; ++i)
    #pragma unroll
    for (int j = 0; j < 4; ++j) acc[i][j] = z4;

  short8 A[12];                  // single A buffer, 48 VGPR
  // prologue: stage period 0 (chunks 0,1)
  STAGE_B(0, 0, 0);
  STAGE_B(0, 1, 1);
  VWAIT(0);
  __builtin_amdgcn_s_barrier();

  #pragma unroll
  for (int p = 0; p < 8; ++p) {
    LOAD_A(A, 2 * p);
    if (p < 7) STAGE_B((p + 1) & 1, 0, 2 * p + 2);
    __builtin_amdgcn_sched_barrier(0);
    MFMA_STEP(A, p & 1, 0);      // compiler waits A with counted vmcnt
    __builtin_amdgcn_sched_barrier(0);
    LOAD_A(A, 2 * p + 1);
    if (p < 7) STAGE_B((p + 1) & 1, 1, 2 * p + 3);
    __builtin_amdgcn_sched_barrier(0);
    MFMA_STEP(A, p & 1, 1);
    __builtin_amdgcn_sched_barrier(0);
    VWAIT(0);                    // drains only loads issued >=1 MFMA-step ago
    __builtin_amdgcn_s_barrier();
  }

  // epilogue: *coef + bias, store bf16 y into d_out rows (u16 stride 4096)
  int lq = lane >> 4, lrr = lane & 15;
  #pragma unroll
  for (int rg = 0; rg < 4; ++rg) {
    int o2 = o0 + wr * 64 + rg * 16 + lq * 4;
    float c0 = coef[b * 512 + o2 + 0], c1 = coef[b * 512 + o2 + 1];
    float c2 = coef[b * 512 + o2 + 2], c3 = coef[b * 512 + o2 + 3];
    float b0 = convb[o2 + 0], b1 = convb[o2 + 1];
    float b2 = convb[o2 + 2], b3 = convb[o2 + 3];
    #pragma unroll
    for (int cg = 0; cg < 4; ++cg) {
      int l = l0 + wc * 64 + cg * 16 + lrr;
      y[((size_t)b * 512 + o2 + 0) * 4096 + l] = f2bf(acc[rg][cg][0] * c0 + b0);
      y[((size_t)b * 512 + o2 + 1) * 4096 + l] = f2bf(acc[rg][cg][1] * c1 + b1);
      y[((size_t)b * 512 + o2 + 2) * 4096 + l] = f2bf(acc[rg][cg][2] * c2 + b2);
      y[((size_t)b * 512 + o2 + 3) * 4096 + l] = f2bf(acc[rg][cg][3] * c3 + b3);
    }
  }
}

// ------- halfband up-LPF -> lrelu*sqrt2 -> halfband down-LPF, decimated ------
// LDS-free: each thread computes 8 outputs from y[m0-8..m0+15] (3 uint4
// loads, overlapping windows -> L1 hits). Edge masking on threads 0/255 only.
struct Taps { float f[8]; };

__global__ __launch_bounds__(256) void k_filter(const unsigned short* __restrict__ ybuf,
    float* __restrict__ out, Taps tp) {
  int ch = blockIdx.x;
  int tir = threadIdx.x;
  int m0 = tir * 8;
  const unsigned short* yr = ybuf + (size_t)ch * 4096;
  uint4 z; z.x = 0u; z.y = 0u; z.z = 0u; z.w = 0u;
  uint4 v0, v1, v2;
  if (tir == 0) {
    v0 = z;
    v1 = *(const uint4*)(yr);
    v2 = *(const uint4*)(yr + 8);
  } else {
    const unsigned short* p = yr + m0 - 8;
    v0 = *(const uint4*)(p);
    v1 = *(const uint4*)(p + 8);
    v2 = *(const uint4*)(p + 16);
    if (tir == 255) v2 = z;
  }
  float f[24];
  {
    unsigned int wv[12] = {v0.x, v0.y, v0.z, v0.w, v1.x, v1.y, v1.z, v1.w,
                           v2.x, v2.y, v2.z, v2.w};
    #pragma unroll
    for (int s = 0; s < 12; ++s) {
      f[2 * s]     = bf2f((unsigned short)(wv[s] & 0xffffu));
      f[2 * s + 1] = bf2f((unsigned short)(wv[s] >> 16));
    }
  }
  // f[s] = y[m0 - 8 + s]
  const float s2 = 1.41421356237309515f;
  float ao[15];
  #pragma unroll
  for (int vv = 0; vv < 15; ++vv) {
    float u = 0.f;
    #pragma unroll
    for (int p = 0; p < 8; ++p) u += tp.f[p] * f[vv + p + 1];
    float a = (u >= 0.f ? u : 0.1f * u) * s2;
    ao[vv] = ((unsigned)(m0 - 4 + vv) < 2048u) ? a : 0.f;
  }
  const float ce = 0.35355339059327379f;   // 0.5 * sqrt2 * 0.5
  float res[8];
  #pragma unroll
  for (int w = 0; w < 8; ++w) {
    float yv = f[w + 8];
    float s = ce * (yv >= 0.f ? yv : 0.1f * yv);
    #pragma unroll
    for (int q = 0; q < 8; ++q) s += tp.f[q] * ao[w + q];
    res[w] = s;
  }
  float4 o0; o0.x = res[0]; o0.y = res[1]; o0.z = res[2]; o0.w = res[3];
  float4 o1; o1.x = res[4]; o1.y = res[5]; o1.z = res[6]; o1.w = res[7];
  float* orow = out + (size_t)ch * 2048 + m0;
  *(float4*)orow = o0;
  *((float4*)orow + 1) = o1;
}

// ------------------------------- host side -----------------------------------
static double bessel_i0(double x) {
  double s = 1.0, term = 1.0;
  for (int m = 1; m < 30; ++m) {
    double h = x * 0.5 / (double)m;
    term *= h * h;
    s += term;
  }
  return s;
}

extern "C" void kernel_launch(void* const* d_in, const int* in_sizes, int n_in,
                              void* d_out, int out_size, void* d_ws, size_t ws_size,
                              hipStream_t stream) {
  (void)in_sizes; (void)n_in; (void)out_size; (void)ws_size;
  const float* x  = (const float*)d_in[0];
  const float* w  = (const float*)d_in[1];
  const float* aw = (const float*)d_in[2];
  const float* ab = (const float*)d_in[3];
  const float* cw = (const float*)d_in[4];
  const float* cb = (const float*)d_in[5];
  const float* ne = (const float*)d_in[6];
  float* out = (float*)d_out;
  char* ws = (char*)d_ws;

  float* ssum = (float*)(ws + 0);
  float* cond = (float*)(ws + 4096);
  float* coef = (float*)(ws + 36864);
  float* rinv = (float*)(ws + 69632);
  unsigned short* wpack = (unsigned short*)(ws + 73728);   // 3,145,728 B
  float* W2 = (float*)(ws + 3219456);                      // 1,048,576 B
  unsigned short* xsT = (unsigned short*)(ws + 4268032);   // 33,587,200 B

  hipMemsetAsync(ssum, 0, 4, stream);
  k_pre1<<<640, 256, 0, stream>>>(w, aw, ab, cw, cond, ssum, W2, rinv, wpack);
  k_pre2<<<4352, 256, 0, stream>>>(x, W2, cond, rinv, ssum, ne, coef, xsT);
  k_main<<<dim3(16, 4, 16), 256, 0, stream>>>(xsT, wpack, coef, cb, (unsigned short*)d_out);

  Taps tp;
  {
    double beta = 2.5;
    double i0b = bessel_i0(beta);
    for (int p = 0; p < 8; ++p) {
      int j = 2 * p + 1;          // odd tap index in 0..16
      int n = j - 8;              // -7..7 odd
      double f = sin(0.5 * M_PI * (double)n) / (M_PI * (double)n + 1e-8);
      double rr = (double)(j - 8) / 8.0;
      double win = bessel_i0(beta * sqrt(1.0 - rr * rr)) / i0b;
      tp.f[p] = (float)(win * f);
    }
  }
  k_filter<<<8192, 256, 0, stream>>>((const unsigned short*)d_out, out, tp);
}

// Round 6
// 196.478 us; speedup vs baseline: 1.0591x; 1.0591x over previous
//
#include <hip/hip_runtime.h>
#include <cmath>

typedef __attribute__((ext_vector_type(8))) short short8;
typedef __attribute__((ext_vector_type(4))) float f32x4;

static __device__ __forceinline__ unsigned short f2bf(float x) {
  unsigned int u = __float_as_uint(x);
  unsigned int r = (u + 0x7FFFu + ((u >> 16) & 1u)) >> 16;
  return (unsigned short)r;
}
static __device__ __forceinline__ float bf2f(unsigned short u) {
  return __uint_as_float(((unsigned int)u) << 16);
}
static __device__ __forceinline__ void glds16(const unsigned short* g, unsigned short* l) {
  __builtin_amdgcn_global_load_lds((const __attribute__((address_space(1))) unsigned int*)(g),
                                   (__attribute__((address_space(3))) unsigned int*)(l), 16, 0, 0);
}

#define VWAIT(n) asm volatile("s_waitcnt vmcnt(" #n ")" ::: "memory")

// ---------- fused: cond = w@aw.T + ab (+ssum), and weight prep ---------------
__global__ __launch_bounds__(256) void k_pre1(const float* __restrict__ w,
    const float* __restrict__ aw, const float* __restrict__ ab,
    const float* __restrict__ cw, float* __restrict__ cond, float* __restrict__ ssum,
    float* __restrict__ W2, float* __restrict__ rinv, unsigned short* __restrict__ wpack) {
  __shared__ float red[4];
  int bid = blockIdx.x, t = threadIdx.x;
  if (bid < 128) {
    int outp = bid * 64 + (t >> 2);
    int sub = t & 3;
    int b = outp >> 9, i = outp & 511;
    const float4* wr = (const float4*)(w + b * 512);
    const float4* ar = (const float4*)(aw + i * 512);
    float acc = 0.f;
    #pragma unroll
    for (int jj = 0; jj < 32; ++jj) {
      int j = sub + jj * 4;
      float4 a = ar[j], v = wr[j];
      acc += a.x * v.x + a.y * v.y + a.z * v.z + a.w * v.w;
    }
    acc += __shfl_xor(acc, 1);
    acc += __shfl_xor(acc, 2);
    float s = 0.f;
    if (sub == 0) {
      float c = acc + ab[i];
      cond[outp] = c;
      s = c * c;
    }
    #pragma unroll
    for (int off = 4; off <= 32; off <<= 1) s += __shfl_xor(s, off);
    if ((t & 63) == 0) atomicAdd(ssum, s);
  } else {
    int o = bid - 128;
    const float* row = cw + o * 1536;
    float local = 0.f;
    for (int r = 0; r < 2; ++r) {
      int i = t + 256 * r;
      float a = row[3 * i], b = row[3 * i + 1], c = row[3 * i + 2];
      float w2 = a * a + b * b + c * c;
      W2[o * 512 + i] = w2;
      local += w2;
      int chunk = i >> 5;
      int laneo = (((i >> 3) & 3) << 4) + (o & 15);
      int e = i & 7;
      int base = (chunk * 32 + (o >> 4)) * 512 + laneo * 8 + e;  // k=0
      wpack[base] = f2bf(a);
      wpack[base + 16 * 32 * 512] = f2bf(b);        // k=1
      wpack[base + 2 * 16 * 32 * 512] = f2bf(c);    // k=2
    }
    #pragma unroll
    for (int off = 32; off >= 1; off >>= 1) local += __shfl_down(local, off);
    if ((t & 63) == 0) red[t >> 6] = local;
    __syncthreads();
    if (t == 0) {
      float m = red[0] + red[1] + red[2] + red[3];
      rinv[o] = rsqrtf(m * (1.f / 1536.f));
    }
  }
}

// ---------- fused: demod coef, and xsT transpose/pack ------------------------
__global__ __launch_bounds__(256) void k_pre2(const float* __restrict__ x,
    const float* __restrict__ W2, const float* __restrict__ cond,
    const float* __restrict__ rinv, const float* __restrict__ ssum,
    const float* __restrict__ nrm, float* __restrict__ coef,
    unsigned short* __restrict__ xsT) {
  __shared__ float shb[64 * 65];
  int bid = blockIdx.x, t = threadIdx.x;
  if (bid < 256) {
    int og = bid & 15, b = bid >> 4;
    int o = og * 32 + (t >> 3);
    int il = t & 7;
    float c0 = cond[b * 512 + t];
    float c1 = cond[b * 512 + t + 256];
    shb[t] = c0 * c0;
    shb[t + 256] = c1 * c1;
    __syncthreads();
    float acc = 0.f;
    #pragma unroll
    for (int jj = 0; jj < 16; ++jj) {
      int i = jj * 32 + il * 4;
      float4 wv = *(const float4*)(W2 + o * 512 + i);
      acc += wv.x * shb[i] + wv.y * shb[i + 1] + wv.z * shb[i + 2] + wv.w * shb[i + 3];
    }
    acc += __shfl_xor(acc, 1);
    acc += __shfl_xor(acc, 2);
    acc += __shfl_xor(acc, 4);
    if (il == 0) {
      float inv_ms = 8192.f / ssum[0];
      float ro = rinv[o];
      coef[b * 512 + o] = ro * rsqrtf(ro * ro * acc * inv_ms + 1e-8f);
    }
  } else {
    int xb = bid - 256;
    int lb = xb & 31, ib = (xb >> 5) & 7, b = xb >> 8;
    float (*tile)[65] = (float(*)[65])shb;
    int l0 = lb * 64, i0 = ib * 64;
    float sc = rsqrtf(ssum[0] * (1.f / 8192.f)) * rsqrtf(nrm[0]);
    int tr = t >> 4, tc = (t & 15) * 4;
    #pragma unroll
    for (int rr = 0; rr < 4; ++rr) {
      int il = rr * 16 + tr;
      float se = cond[b * 512 + i0 + il] * sc;
      float4 v = *(const float4*)(x + ((size_t)b * 512 + i0 + il) * 2048 + l0 + tc);
      tile[il][tc + 0] = v.x * se;
      tile[il][tc + 1] = v.y * se;
      tile[il][tc + 2] = v.z * se;
      tile[il][tc + 3] = v.w * se;
    }
    __syncthreads();
    int lr = t >> 3, ic = (t & 7) * 8;
    #pragma unroll
    for (int rr = 0; rr < 2; ++rr) {
      int ll = rr * 32 + lr;
      uint4 u;
      unsigned int pk[4];
      #pragma unroll
      for (int j = 0; j < 4; ++j) {
        unsigned short lo = f2bf(tile[ic + 2 * j][ll]);
        unsigned short hi = f2bf(tile[ic + 2 * j + 1][ll]);
        pk[j] = (unsigned int)lo | ((unsigned int)hi << 16);
      }
      u.x = pk[0]; u.y = pk[1]; u.z = pk[2]; u.w = pk[3];
      *(uint4*)(xsT + ((size_t)b * 2050 + 1 + l0 + ll) * 512 + i0 + ic) = u;
    }
    if (lb == 0 && t < 8) {
      uint4 z; z.x = 0; z.y = 0; z.z = 0; z.w = 0;
      *(uint4*)(xsT + ((size_t)b * 2050) * 512 + i0 + t * 8) = z;
    }
    if (lb == 31 && t < 8) {
      uint4 z; z.x = 0; z.y = 0; z.z = 0; z.w = 0;
      *(uint4*)(xsT + ((size_t)b * 2050 + 2049) * 512 + i0 + t * 8) = z;
    }
  }
}

// ----------------- main: y[b,o,l] = conv(xs, W)*coef + bias ------------------
// Block tile 128o x 256l, 4 waves (2o x 2l), WAVE tile 64o x 128l:
// acc[4][8] (128 VGPR), 96 MFMA per wave-chunk for 12 A-frag + 24 B-frag
// reads (reads/MFMA 0.375 vs 0.5 before; A L2-traffic per FLOP halved).
// Grid 512 blocks = exactly 2/CU, single batch. A single-buffered in regs;
// B double-buffered LDS (2 x 16.5 KB), staged via global_load_lds with
// inverse-swizzled source. setprio(1) around MFMA cluster (T5; 2 unsynced
// blocks/CU give role diversity). (256,2): R3 showed min-waves=3 spills.
#define STAGE_B(buf, c) { \
  _Pragma("unroll") for (int j_ = 0; j_ < 5; ++j_) { \
    int sb_ = wave * 258 + ((j_ < 4) ? j_ * 64 : 256); \
    int s_ = sb_ + ((j_ < 4) ? lane : (lane & 1)); \
    if (j_ < 4 || lane < 2) { \
      int c0_ = ((s_ >> 2) ^ (s_ >> 4)) & 1; \
      int col_ = ((s_ >> 3) << 1) | c0_; \
      int q_ = ((s_ ^ c0_) & 1) | ((((s_ >> 1) ^ (s_ >> 3)) & 1) << 1); \
      const unsigned short* src_ = xsT + ((size_t)b * 2050 + l0 + col_) * 512 + (c) * 32 + q_ * 8; \
      glds16(src_, &Bl[buf][sb_ * 8]); \
    } \
  } }

#define LOAD_A(Ar, c) { \
  _Pragma("unroll") for (int k_ = 0; k_ < 3; ++k_) \
  _Pragma("unroll") for (int rg_ = 0; rg_ < 4; ++rg_) \
    Ar[k_ * 4 + rg_] = *(const short8*)(wpack + ((size_t)((k_ * 16 + (c)) * 32 + ob * 8 + wr * 4 + rg_)) * 512 + lane * 8); }

// one k-tap, half the l-tiles (4 cg): 4 b128 reads + 16 MFMA
#define MFMA_HALF(Ar, buf, k, cgb) { \
  short8 bfr_[4]; \
  _Pragma("unroll") for (int c2_ = 0; c2_ < 4; ++c2_) { \
    int col_ = wc * 128 + ((cgb) + c2_) * 16 + (lane & 15) + (k); \
    int byte_ = (col_ * 64 + ((lane >> 4) << 4)) ^ ((col_ & 7) << 4); \
    bfr_[c2_] = *(const short8*)((const char*)Bl[buf] + byte_); \
  } \
  _Pragma("unroll") for (int rg_ = 0; rg_ < 4; ++rg_) \
    _Pragma("unroll") for (int c2_ = 0; c2_ < 4; ++c2_) \
      acc[rg_][(cgb) + c2_] = __builtin_amdgcn_mfma_f32_16x16x32_bf16(Ar[(k) * 4 + rg_], bfr_[c2_], acc[rg_][(cgb) + c2_], 0, 0, 0); \
  }

#define MFMA_CHUNK(Ar, buf) { \
  _Pragma("unroll") for (int k_ = 0; k_ < 3; ++k_) { \
    MFMA_HALF(Ar, buf, k_, 0); \
    MFMA_HALF(Ar, buf, k_, 4); \
  } }

__global__ __launch_bounds__(256, 2) void k_main(const unsigned short* __restrict__ xsT,
    const unsigned short* __restrict__ wpack, const float* __restrict__ coef,
    const float* __restrict__ convb, unsigned short* __restrict__ y) {
  int lb = blockIdx.x, ob = blockIdx.y, b = blockIdx.z;
  int t = threadIdx.x, lane = t & 63, wave = t >> 6;
  int wr = wave >> 1, wc = wave & 1;
  int l0 = lb * 256, o0 = ob * 128;
  __shared__ __align__(16) unsigned short Bl[2][8256];   // 2 x 16,512 B
  f32x4 acc[4][8];
  f32x4 z4 = {0.f, 0.f, 0.f, 0.f};
  #pragma unroll
  for (int i = 0; i < 4; ++i)
    #pragma unroll
    for (int j = 0; j < 8; ++j) acc[i][j] = z4;

  short8 A[12];                  // single A buffer, 48 VGPR
  STAGE_B(0, 0);
  VWAIT(0);
  __builtin_amdgcn_s_barrier();

  #pragma unroll 2
  for (int c = 0; c < 16; ++c) {
    LOAD_A(A, c);
    if (c < 15) STAGE_B((c + 1) & 1, c + 1);
    __builtin_amdgcn_sched_barrier(0);
    __builtin_amdgcn_s_setprio(1);
    MFMA_CHUNK(A, c & 1);
    __builtin_amdgcn_s_setprio(0);
    __builtin_amdgcn_sched_barrier(0);
    VWAIT(0);                    // drains loads issued one MFMA-phase ago
    __builtin_amdgcn_s_barrier();
  }

  // epilogue: *coef + bias, store bf16 y into d_out rows (u16 stride 4096)
  int lq = lane >> 4, lrr = lane & 15;
  #pragma unroll
  for (int rg = 0; rg < 4; ++rg) {
    int o2 = o0 + wr * 64 + rg * 16 + lq * 4;
    float c0 = coef[b * 512 + o2 + 0], c1 = coef[b * 512 + o2 + 1];
    float c2 = coef[b * 512 + o2 + 2], c3 = coef[b * 512 + o2 + 3];
    float b0 = convb[o2 + 0], b1 = convb[o2 + 1];
    float b2 = convb[o2 + 2], b3 = convb[o2 + 3];
    #pragma unroll
    for (int cg = 0; cg < 8; ++cg) {
      int l = l0 + wc * 128 + cg * 16 + lrr;
      y[((size_t)b * 512 + o2 + 0) * 4096 + l] = f2bf(acc[rg][cg][0] * c0 + b0);
      y[((size_t)b * 512 + o2 + 1) * 4096 + l] = f2bf(acc[rg][cg][1] * c1 + b1);
      y[((size_t)b * 512 + o2 + 2) * 4096 + l] = f2bf(acc[rg][cg][2] * c2 + b2);
      y[((size_t)b * 512 + o2 + 3) * 4096 + l] = f2bf(acc[rg][cg][3] * c3 + b3);
    }
  }
}

// ------- halfband up-LPF -> lrelu*sqrt2 -> halfband down-LPF, decimated ------
// LDS-free: each thread computes 8 outputs from y[m0-8..m0+15] (3 uint4
// loads, overlapping windows -> L1 hits). Edge masking on threads 0/255 only.
struct Taps { float f[8]; };

__global__ __launch_bounds__(256) void k_filter(const unsigned short* __restrict__ ybuf,
    float* __restrict__ out, Taps tp) {
  int ch = blockIdx.x;
  int tir = threadIdx.x;
  int m0 = tir * 8;
  const unsigned short* yr = ybuf + (size_t)ch * 4096;
  uint4 z; z.x = 0u; z.y = 0u; z.z = 0u; z.w = 0u;
  uint4 v0, v1, v2;
  if (tir == 0) {
    v0 = z;
    v1 = *(const uint4*)(yr);
    v2 = *(const uint4*)(yr + 8);
  } else {
    const unsigned short* p = yr + m0 - 8;
    v0 = *(const uint4*)(p);
    v1 = *(const uint4*)(p + 8);
    v2 = *(const uint4*)(p + 16);
    if (tir == 255) v2 = z;
  }
  float f[24];
  {
    unsigned int wv[12] = {v0.x, v0.y, v0.z, v0.w, v1.x, v1.y, v1.z, v1.w,
                           v2.x, v2.y, v2.z, v2.w};
    #pragma unroll
    for (int s = 0; s < 12; ++s) {
      f[2 * s]     = bf2f((unsigned short)(wv[s] & 0xffffu));
      f[2 * s + 1] = bf2f((unsigned short)(wv[s] >> 16));
    }
  }
  // f[s] = y[m0 - 8 + s]
  const float s2 = 1.41421356237309515f;
  float ao[15];
  #pragma unroll
  for (int vv = 0; vv < 15; ++vv) {
    float u = 0.f;
    #pragma unroll
    for (int p = 0; p < 8; ++p) u += tp.f[p] * f[vv + p + 1];
    float a = (u >= 0.f ? u : 0.1f * u) * s2;
    ao[vv] = ((unsigned)(m0 - 4 + vv) < 2048u) ? a : 0.f;
  }
  const float ce = 0.35355339059327379f;   // 0.5 * sqrt2 * 0.5
  float res[8];
  #pragma unroll
  for (int w = 0; w < 8; ++w) {
    float yv = f[w + 8];
    float s = ce * (yv >= 0.f ? yv : 0.1f * yv);
    #pragma unroll
    for (int q = 0; q < 8; ++q) s += tp.f[q] * ao[w + q];
    res[w] = s;
  }
  float4 o0; o0.x = res[0]; o0.y = res[1]; o0.z = res[2]; o0.w = res[3];
  float4 o1; o1.x = res[4]; o1.y = res[5]; o1.z = res[6]; o1.w = res[7];
  float* orow = out + (size_t)ch * 2048 + m0;
  *(float4*)orow = o0;
  *((float4*)orow + 1) = o1;
}

// ------------------------------- host side -----------------------------------
static double bessel_i0(double x) {
  double s = 1.0, term = 1.0;
  for (int m = 1; m < 30; ++m) {
    double h = x * 0.5 / (double)m;
    term *= h * h;
    s += term;
  }
  return s;
}

extern "C" void kernel_launch(void* const* d_in, const int* in_sizes, int n_in,
                              void* d_out, int out_size, void* d_ws, size_t ws_size,
                              hipStream_t stream) {
  (void)in_sizes; (void)n_in; (void)out_size; (void)ws_size;
  const float* x  = (const float*)d_in[0];
  const float* w  = (const float*)d_in[1];
  const float* aw = (const float*)d_in[2];
  const float* ab = (const float*)d_in[3];
  const float* cw = (const float*)d_in[4];
  const float* cb = (const float*)d_in[5];
  const float* ne = (const float*)d_in[6];
  float* out = (float*)d_out;
  char* ws = (char*)d_ws;

  float* ssum = (float*)(ws + 0);
  float* cond = (float*)(ws + 4096);
  float* coef = (float*)(ws + 36864);
  float* rinv = (float*)(ws + 69632);
  unsigned short* wpack = (unsigned short*)(ws + 73728);   // 3,145,728 B
  float* W2 = (float*)(ws + 3219456);                      // 1,048,576 B
  unsigned short* xsT = (unsigned short*)(ws + 4268032);   // 33,587,200 B

  hipMemsetAsync(ssum, 0, 4, stream);
  k_pre1<<<640, 256, 0, stream>>>(w, aw, ab, cw, cond, ssum, W2, rinv, wpack);
  k_pre2<<<4352, 256, 0, stream>>>(x, W2, cond, rinv, ssum, ne, coef, xsT);
  k_main<<<dim3(8, 4, 16), 256, 0, stream>>>(xsT, wpack, coef, cb, (unsigned short*)d_out);

  Taps tp;
  {
    double beta = 2.5;
    double i0b = bessel_i0(beta);
    for (int p = 0; p < 8; ++p) {
      int j = 2 * p + 1;          // odd tap index in 0..16
      int n = j - 8;              // -7..7 odd
      double f = sin(0.5 * M_PI * (double)n) / (M_PI * (double)n + 1e-8);
      double rr = (double)(j - 8) / 8.0;
      double win = bessel_i0(beta * sqrt(1.0 - rr * rr)) / i0b;
      tp.f[p] = (float)(win * f);
    }
  }
  k_filter<<<8192, 256, 0, stream>>>((const unsigned short*)d_out, out, tp);
}